// Round 7
// baseline (304.474 us; speedup 1.0000x reference)
//
#include <hip/hip_runtime.h>

// SigWassersteinMetric: depth-4 path signature, C=10, T=256.
//   original: (4096, 256, 10) f32; generated: (1024, 256, 10) f32; sample_idx: (1024,)
// 2048 blocks (1024 sampled originals + 1024 generated), 128 threads each.
//
// Horner-factored Chen step (verified rounds 2/4/5/6):
//   A2 = S2 + (S1 + v/4) (x) v/3
//   B2 = S2 + (S1 + v/3) (x) v/2
//   A3 = S3 + A2 (x) v/2 ;  S4' = S4 + A3 (x) v ;  S3' = S3 + B2 (x) v
//   S2' = S2 + (S1 + v/2) (x) v ;  S1 closed-form in epilogue.
//
// ROUND-7: __launch_bounds__(128, 2) -> 256-reg/wave budget. Rounds 5/6 ran
// with (128,4) = 128-reg cap; allocator split 64 VGPR + AGPRs for the
// 80-float acc array, inserting v_accvgpr movs (1.5x issue inflation) and
// ~31 MB scratch writes. True footprint ~135-160 regs; (128,2) fits it in
// pure VGPRs. VALU-bound with 80 independent FMA chains -> 2-3 waves/SIMD
// suffices to saturate issue.
#define T_LEN 256
#define C_DIM 10
#define NSTEP 255
#define BSZ   1024
#define NBLK  2048
#define D1 10
#define D2 100
#define D3 1000
#define DTOT 11110
#define PATH_ELEMS (T_LEN * C_DIM)   // 2560
#define DX_ELEMS (NSTEP * C_DIM)     // 2550
#define DXROW 12                     // padded dx row stride (48 B, 16B-aligned)

__global__ __launch_bounds__(128, 2) void sig_accum_kernel(
    const float* __restrict__ original,
    const float* __restrict__ generated,
    const int* __restrict__ sample_idx,
    float* __restrict__ ws, int nrep, int store_mode)
{
    const int tid = threadIdx.x;
    const int b   = blockIdx.x;

    __shared__ float s_dx[NSTEP * DXROW];  // 12240 B (only LDS use)

    const float* path;
    float sign;
    if (b < BSZ) { path = original + (size_t)sample_idx[b] * PATH_ELEMS; sign = 1.0f; }
    else         { path = generated + (size_t)(b - BSZ) * PATH_ELEMS;    sign = -1.0f; }

    for (int idx = tid; idx < DX_ELEMS; idx += 128) {
        int t = idx / C_DIM, c = idx - t * C_DIM;
        s_dx[t * DXROW + c] = path[idx + C_DIM] - path[idx];
    }
    __syncthreads();   // the ONLY barrier

    const int m0  = 4 * tid;                 // valid tid<125
    const int k0  = m0 / 100;                // 0..4
    const int ij0 = m0 - k0 * 100;           // 0,4,...,96
    const int ia  = ij0 / 10;                // i for q0,q1
    const int ib  = (ij0 + 2) / 10;          // i for q2,q3
    const int j0  = ij0 - ia * 10;           // even
    const int jc  = (j0 + 2) % 10;           // even

    float s1a = 0.0f, s1b = 0.0f;
    float s2[4] = {0.0f, 0.0f, 0.0f, 0.0f};
    float s3[8];
    float acc[8][10];                        // rows 0-3: k0; rows 4-7: k0+5
    #pragma unroll
    for (int r = 0; r < 8; ++r) {
        s3[r] = 0.0f;
        #pragma unroll
        for (int l = 0; l < 10; ++l) acc[r][l] = 0.0f;
    }

    if (tid < 125) {
        const float* vrow = s_dx;
        #pragma unroll 1
        for (int t = 0; t < NSTEP; ++t, vrow += DXROW) {
            // ---- LDS loads (read-only, fixed per-thread offsets) ----
            const float4 va = *(const float4*)(vrow);       // v0..v3
            const float4 vb = *(const float4*)(vrow + 4);   // v4..v7
            const float2 vc = *(const float2*)(vrow + 8);   // v8,v9
            const float2 vjA = *(const float2*)(vrow + j0); // vj q0,q1 (8B aligned)
            const float2 vjB = *(const float2*)(vrow + jc); // vj q2,q3 (8B aligned)
            const float via = vrow[ia];
            const float vib = vrow[ib];
            const float vk0 = vrow[k0];
            const float vk1 = vrow[k0 + 5];

            const float vv[10] = {va.x, va.y, va.z, va.w,
                                  vb.x, vb.y, vb.z, vb.w, vc.x, vc.y};
            const float vj[4] = {vjA.x, vjA.y, vjB.x, vjB.y};
            const float vk0h = vk0 * 0.5f;
            const float vk1h = vk1 * 0.5f;

            // ---- q-interleaved level-2/3/4, all registers ----
            #pragma unroll
            for (int q = 0; q < 4; ++q) {
                const float s1q = (q < 2) ? s1a : s1b;
                const float viq = (q < 2) ? via : vib;
                const float a2q = s2[q] + (s1q + viq * 0.25f)        * (vj[q] * (1.0f / 3.0f));
                const float b2q = s2[q] + (s1q + viq * (1.0f/3.0f))  * (vj[q] * 0.5f);
                s2[q]           = s2[q] + (s1q + viq * 0.5f)         * vj[q];

                const float a3x = s3[q] + a2q * vk0h;
                s3[q] += b2q * vk0;
                #pragma unroll
                for (int l = 0; l < 10; ++l) acc[q][l] += a3x * vv[l];

                const float a3y = s3[4 + q] + a2q * vk1h;
                s3[4 + q] += b2q * vk1;
                #pragma unroll
                for (int l = 0; l < 10; ++l) acc[4 + q][l] += a3y * vv[l];
            }
            s1a += via;
            s1b += vib;
        }
    }

    // ---- Epilogue ----
    // Level-1 closed form: S1[c] = x[T-1][c] - x[0][c] (two global reads).
    // S2 replicas agree across k0 groups; threads 0..24 (ij0 = 4*tid) write them.
    if (store_mode) {
        float* orow = ws + (size_t)b * DTOT;
        if (tid < D1) orow[tid] = sign * (path[(T_LEN - 1) * C_DIM + tid] - path[tid]);
        if (tid < 25) {
            #pragma unroll
            for (int q = 0; q < 4; ++q) orow[D1 + ij0 + q] = sign * s2[q];
        }
        if (tid < 125) {
            #pragma unroll
            for (int ch = 0; ch < 2; ++ch) {
                const int kk = k0 + 5 * ch;
                #pragma unroll
                for (int r = 0; r < 4; ++r) {
                    const int idx3 = (ij0 + r) * 10 + kk;
                    orow[D1 + D2 + idx3] = sign * s3[ch * 4 + r];
                    float* p4 = orow + D1 + D2 + D3 + (size_t)idx3 * 10;
                    #pragma unroll
                    for (int l = 0; l < 10; l += 2)
                        *(float2*)&p4[l] = make_float2(sign * acc[ch * 4 + r][l],
                                                       sign * acc[ch * 4 + r][l + 1]);
                }
            }
        }
    } else {
        float* base = ws + (size_t)(b % nrep) * DTOT;
        if (tid < D1)
            atomicAdd(&base[tid], sign * (path[(T_LEN - 1) * C_DIM + tid] - path[tid]));
        if (tid < 25) {
            #pragma unroll
            for (int q = 0; q < 4; ++q) atomicAdd(&base[D1 + ij0 + q], sign * s2[q]);
        }
        if (tid < 125) {
            #pragma unroll
            for (int ch = 0; ch < 2; ++ch) {
                const int kk = k0 + 5 * ch;
                #pragma unroll
                for (int r = 0; r < 4; ++r) {
                    const int idx3 = (ij0 + r) * 10 + kk;
                    atomicAdd(&base[D1 + D2 + idx3], sign * s3[ch * 4 + r]);
                    #pragma unroll
                    for (int l = 0; l < 10; ++l)
                        atomicAdd(&base[D1 + D2 + D3 + idx3 * 10 + l],
                                  sign * acc[ch * 4 + r][l]);
                }
            }
        }
    }
}

// Stage 1: block sums 32 rows for a 512-float d-tile (float2 lanes, coalesced),
// atomically accumulates into accvec[DTOT]. Grid: (ceil(5555/256), 64).
__global__ __launch_bounds__(256) void sig_sum_kernel(
    const float* __restrict__ ws, float* __restrict__ accvec)
{
    const int d2 = blockIdx.x * 256 + threadIdx.x;   // float2 index, DTOT/2 = 5555
    if (d2 >= DTOT / 2) return;
    const float* p = ws + (size_t)(blockIdx.y * 32) * DTOT + 2 * d2;
    float sx = 0.0f, sy = 0.0f;
    #pragma unroll
    for (int r = 0; r < 32; ++r) {
        const float2 v = *(const float2*)(p + (size_t)r * DTOT);
        sx += v.x; sy += v.y;
    }
    atomicAdd(&accvec[2 * d2], sx);
    atomicAdd(&accvec[2 * d2 + 1], sy);
}

// Stage 2: sum of squares of accvec -> sumsq; last block computes the norm
// (device-scope counter + fence replaces a separate 1-block launch).
__global__ __launch_bounds__(256) void sig_sumsq_kernel(
    const float* __restrict__ accvec, float* __restrict__ sumsq,
    unsigned int* __restrict__ counter, float* __restrict__ out, int nblocks)
{
    const int d = blockIdx.x * 256 + threadIdx.x;
    float s = 0.0f;
    if (d < DTOT) { float v = accvec[d]; s = v * v; }
    for (int off = 32; off > 0; off >>= 1) s += __shfl_down(s, off, 64);
    __shared__ float red[4];
    __shared__ unsigned int lastflag;
    if ((threadIdx.x & 63) == 0) red[threadIdx.x >> 6] = s;
    __syncthreads();
    if (threadIdx.x == 0) {
        atomicAdd(sumsq, red[0] + red[1] + red[2] + red[3]);
        __threadfence();
        lastflag = (atomicAdd(counter, 1u) == (unsigned int)(nblocks - 1));
    }
    __syncthreads();
    if (threadIdx.x == 0 && lastflag) {
        __threadfence();
        out[0] = sqrtf(*(volatile float*)sumsq) * (1.0f / (float)BSZ);
    }
}

// Fallback reduce for small-ws atomic-replica modes (writes out directly).
__global__ __launch_bounds__(256) void sig_reduce_kernel(
    const float* __restrict__ ws, int nrows, float* __restrict__ sumsq,
    unsigned int* __restrict__ counter, float* __restrict__ out, int nblocks)
{
    const int d = blockIdx.x * 256 + threadIdx.x;
    float s = 0.0f;
    if (d < DTOT) {
        for (int r = 0; r < nrows; ++r) s += ws[(size_t)r * DTOT + d];
        s = s * s;
    }
    for (int off = 32; off > 0; off >>= 1) s += __shfl_down(s, off, 64);
    __shared__ float red[4];
    __shared__ unsigned int lastflag;
    if ((threadIdx.x & 63) == 0) red[threadIdx.x >> 6] = s;
    __syncthreads();
    if (threadIdx.x == 0) {
        atomicAdd(sumsq, red[0] + red[1] + red[2] + red[3]);
        __threadfence();
        lastflag = (atomicAdd(counter, 1u) == (unsigned int)(nblocks - 1));
    }
    __syncthreads();
    if (threadIdx.x == 0 && lastflag) {
        __threadfence();
        out[0] = sqrtf(*(volatile float*)sumsq) * (1.0f / (float)BSZ);
    }
}

extern "C" void kernel_launch(void* const* d_in, const int* in_sizes, int n_in,
                              void* d_out, int out_size, void* d_ws, size_t ws_size,
                              hipStream_t stream) {
    const float* original   = (const float*)d_in[0];
    const float* generated  = (const float*)d_in[1];
    const int*   sample_idx = (const int*)d_in[2];
    float* out = (float*)d_out;
    float* ws  = (float*)d_ws;

    // Layout: rows [0, NBLK*DTOT), accvec [+DTOT), sumsq [+1), counter [+1)
    const size_t need_store = ((size_t)(NBLK + 1) * DTOT + 2) * sizeof(float);

    if (ws_size >= need_store) {
        float* accvec = ws + (size_t)NBLK * DTOT;
        float* sumsq  = accvec + DTOT;
        unsigned int* counter = (unsigned int*)(sumsq + 1);
        hipMemsetAsync(accvec, 0, (DTOT + 2) * sizeof(float), stream);
        sig_accum_kernel<<<NBLK, 128, 0, stream>>>(original, generated, sample_idx,
                                                   ws, 1, 1);
        dim3 g1((DTOT / 2 + 255) / 256, 64);
        sig_sum_kernel<<<g1, 256, 0, stream>>>(ws, accvec);
        const int nb2 = (DTOT + 255) / 256;
        sig_sumsq_kernel<<<nb2, 256, 0, stream>>>(accvec, sumsq, counter, out, nb2);
    } else {
        int nrep = 1;
        if (ws_size >= ((size_t)64 * DTOT + 2) * sizeof(float)) nrep = 64;
        else if (ws_size >= ((size_t)8 * DTOT + 2) * sizeof(float)) nrep = 8;
        float* sumsq = ws + (size_t)nrep * DTOT;
        unsigned int* counter = (unsigned int*)(sumsq + 1);
        hipMemsetAsync(ws, 0, ((size_t)nrep * DTOT + 2) * sizeof(float), stream);
        sig_accum_kernel<<<NBLK, 128, 0, stream>>>(original, generated, sample_idx,
                                                   ws, nrep, 0);
        const int nb2 = (DTOT + 255) / 256;
        sig_reduce_kernel<<<nb2, 256, 0, stream>>>(ws, nrep, sumsq, counter, out, nb2);
    }
}